// Round 6
// baseline (396.407 us; speedup 1.0000x reference)
//
#include <hip/hip_runtime.h>

// PointConv fused pipeline v4 (4 dispatches):
//  0. memset: head = -1
//  1. build_cvt: ref_feat fp32->bf16 table (RNE) + per-query linked list
//                (atomicExch) + zero stats
//  2. fused:  per 32-query block:
//             phase A: 16 half-waves x 2 interleaved chains chase lists,
//                      bf16 gather, fp32 accumulate -> LDS tile sA + sPS
//             phase B: GEMM (accF@Wm^T + posdiff@Wp^T + cnt*b)/max(cnt,1)
//                      -> out, + per-channel sum/sumsq atomics -> stats
//  3. bnapply: inline BN-prep from stats + normalize + ReLU in-place

__device__ __forceinline__ float bf_lo(unsigned u) {
  union { unsigned u; float f; } c; c.u = u << 16; return c.f;
}
__device__ __forceinline__ float bf_hi(unsigned u) {
  union { unsigned u; float f; } c; c.u = u & 0xFFFF0000u; return c.f;
}
__device__ __forceinline__ unsigned pack_bf(float x, float y) {
  union { float f; unsigned u; } a, b; a.f = x; b.f = y;
  unsigned lo = (a.u + 0x7FFFu + ((a.u >> 16) & 1u)) >> 16;
  unsigned hi = (b.u + 0x7FFFu + ((b.u >> 16) & 1u)) >> 16;
  return lo | (hi << 16);
}

__global__ __launch_bounds__(256) void k_build_cvt(
    const int* __restrict__ eq, const int* __restrict__ er,
    int* __restrict__ head, int2* __restrict__ node,
    const float4* __restrict__ featf, uint4* __restrict__ featb,
    float* __restrict__ stats, int E_, int n8) {
  int i = blockIdx.x * blockDim.x + threadIdx.x;
  if (i < 256) stats[i] = 0.f;          // zero for k_fused's atomics
  if (i < n8) {
    float4 a = featf[2 * i], b = featf[2 * i + 1];
    uint4 o;
    o.x = pack_bf(a.x, a.y);
    o.y = pack_bf(a.z, a.w);
    o.z = pack_bf(b.x, b.y);
    o.w = pack_bf(b.z, b.w);
    featb[i] = o;
  }
  if (i < E_) {
    int q = eq[i];
    int prev = atomicExch(&head[q], i);
    node[i] = make_int2(prev, er[i]);
  }
}

// One block = 32 queries. Phase A: chase; Phase B: 4x4-microtile GEMM.
__global__ __launch_bounds__(256, 4) void k_fused(
    const int* __restrict__ head, const int2* __restrict__ node,
    const uint4* __restrict__ featb, const float* __restrict__ bxyz,
    const float* __restrict__ qxyz,
    const float* __restrict__ Wm, const float* __restrict__ Wp,
    const float* __restrict__ bm, const float* __restrict__ bp,
    float* __restrict__ out, float* __restrict__ stats, int M_) {
  __shared__ float sA[32 * 132];   // acc tile [32][128], stride 132
  __shared__ float sW[128 * 34];   // W k-tile [128][32] as float2 stride 17
  __shared__ float sPS[32][4];     // per-row {sx, sy, sz, cnt}
  int t = threadIdx.x;
  int q0 = blockIdx.x * 32;
  int hw = t >> 4, l = t & 15;

  // ---- phase A: dual-chain chase (rows hw and hw+16) ----
  {
    int qa = q0 + hw, qb = q0 + hw + 16;
    int ia = (qa < M_) ? head[qa] : -1;
    int ib = (qb < M_) ? head[qb] : -1;
    float aA0=0.f,aA1=0.f,aA2=0.f,aA3=0.f,aA4=0.f,aA5=0.f,aA6=0.f,aA7=0.f;
    float aB0=0.f,aB1=0.f,aB2=0.f,aB3=0.f,aB4=0.f,aB5=0.f,aB6=0.f,aB7=0.f;
    float pA=0.f,cA=0.f,pB=0.f,cB=0.f;
    while (ia >= 0 || ib >= 0) {
      bool da = ia >= 0, db = ib >= 0;
      int2 na, nb; uint4 va, vb;
      if (da) na = node[ia];
      if (db) nb = node[ib];
      if (da) va = featb[(size_t)na.y * 16 + l];
      if (db) vb = featb[(size_t)nb.y * 16 + l];
      if (da) {
        aA0+=bf_lo(va.x); aA1+=bf_hi(va.x); aA2+=bf_lo(va.y); aA3+=bf_hi(va.y);
        aA4+=bf_lo(va.z); aA5+=bf_hi(va.z); aA6+=bf_lo(va.w); aA7+=bf_hi(va.w);
        if (l < 3) pA += bxyz[na.y * 4 + 1 + l];
        cA += 1.f; ia = na.x;
      }
      if (db) {
        aB0+=bf_lo(vb.x); aB1+=bf_hi(vb.x); aB2+=bf_lo(vb.y); aB3+=bf_hi(vb.y);
        aB4+=bf_lo(vb.z); aB5+=bf_hi(vb.z); aB6+=bf_lo(vb.w); aB7+=bf_hi(vb.w);
        if (l < 3) pB += bxyz[nb.y * 4 + 1 + l];
        cB += 1.f; ib = nb.x;
      }
    }
    *(float4*)&sA[hw * 132 + 8 * l]          = make_float4(aA0,aA1,aA2,aA3);
    *(float4*)&sA[hw * 132 + 8 * l + 4]      = make_float4(aA4,aA5,aA6,aA7);
    *(float4*)&sA[(hw + 16) * 132 + 8 * l]     = make_float4(aB0,aB1,aB2,aB3);
    *(float4*)&sA[(hw + 16) * 132 + 8 * l + 4] = make_float4(aB4,aB5,aB6,aB7);
    if (l < 3) { sPS[hw][l] = pA; sPS[hw + 16][l] = pB; }
    if (l == 3) { sPS[hw][3] = cA; sPS[hw + 16][3] = cB; }
  }

  // ---- phase B: GEMM ----
  float acc[4][4];
  #pragma unroll
  for (int i = 0; i < 4; ++i)
    #pragma unroll
    for (int j = 0; j < 4; ++j) acc[i][j] = 0.f;
  int q0l = (t >> 5) << 2;  // row base 0,4,...,28
  int cb = t & 31;          // channel base; thread's channels = cb + 32j
  float2* sW2 = (float2*)sW;                    // row stride 17 float2
  const float2* Wm2 = (const float2*)Wm;        // row stride 64 float2
  for (int kt = 0; kt < 4; ++kt) {
    __syncthreads();   // kt=0: phase A writes visible; kt>0: sW reads done
    #pragma unroll
    for (int i = 0; i < 8; ++i) {   // stage W[:, kt*32 .. kt*32+31]
      int f = t + 256 * i;          // 2048 float2 slots
      int c = f >> 4;
      int kk2 = f & 15;
      sW2[c * 17 + kk2] = Wm2[c * 64 + kt * 16 + kk2];
    }
    __syncthreads();
    #pragma unroll
    for (int kk4 = 0; kk4 < 8; ++kk4) {
      float4 av[4];
      float2 wa[4], wb[4];
      #pragma unroll
      for (int i = 0; i < 4; ++i)
        av[i] = *(const float4*)&sA[(q0l + i) * 132 + kt * 32 + (kk4 << 2)];
      #pragma unroll
      for (int j = 0; j < 4; ++j) {
        int c = cb + 32 * j;
        wa[j] = sW2[c * 17 + kk4 * 2];
        wb[j] = sW2[c * 17 + kk4 * 2 + 1];
      }
      #pragma unroll
      for (int i = 0; i < 4; ++i)
        #pragma unroll
        for (int j = 0; j < 4; ++j) {
          acc[i][j] = fmaf(av[i].x, wa[j].x, acc[i][j]);
          acc[i][j] = fmaf(av[i].y, wa[j].y, acc[i][j]);
          acc[i][j] = fmaf(av[i].z, wb[j].x, acc[i][j]);
          acc[i][j] = fmaf(av[i].w, wb[j].y, acc[i][j]);
        }
    }
  }
  float fcnt[4], inv[4], dx[4], dy[4], dz[4];
  #pragma unroll
  for (int i = 0; i < 4; ++i) {
    int row = q0l + i;
    int q = q0 + row;
    if (q < M_) {
      float fc = sPS[row][3];
      fcnt[i] = fc;
      inv[i] = 1.f / fmaxf(fc, 1.f);
      dx[i] = sPS[row][0] - fc * qxyz[q * 4 + 1];
      dy[i] = sPS[row][1] - fc * qxyz[q * 4 + 2];
      dz[i] = sPS[row][2] - fc * qxyz[q * 4 + 3];
    } else {
      fcnt[i] = 0.f; inv[i] = 1.f; dx[i] = dy[i] = dz[i] = 0.f;
    }
  }
  float psum[4], psq[4];
  #pragma unroll
  for (int j = 0; j < 4; ++j) {
    int c = cb + 32 * j;
    float w0 = Wp[c * 3 + 0], w1 = Wp[c * 3 + 1], w2 = Wp[c * 3 + 2];
    float bb = bm[c] + bp[c];
    float s = 0.f, s2 = 0.f;
    #pragma unroll
    for (int i = 0; i < 4; ++i) {
      int q = q0 + q0l + i;
      float v = acc[i][j] + dx[i] * w0 + dy[i] * w1 + dz[i] * w2 + fcnt[i] * bb;
      float val = v * inv[i];
      if (q >= M_) val = 0.f;       // padded rows contribute zero
      if (q < M_) out[q * 128 + c] = val;
      s += val; s2 += val * val;
    }
    psum[j] = s; psq[j] = s2;
  }
  // block reduction of per-channel partials in reused sA space
  __syncthreads();                  // all sA reads done
  float* red = sA;                  // [0..1023]=sum, [1024..2047]=sumsq
  int rg = t >> 5;                  // row-group 0..7
  #pragma unroll
  for (int j = 0; j < 4; ++j) {
    int c = cb + 32 * j;
    red[c * 8 + rg] = psum[j];
    red[1024 + c * 8 + rg] = psq[j];
  }
  __syncthreads();
  if (t < 128) {
    float s = 0.f, s2 = 0.f;
    #pragma unroll
    for (int r = 0; r < 8; ++r) {
      s += red[t * 8 + r];
      s2 += red[1024 + t * 8 + r];
    }
    atomicAdd(&stats[t], s);
    atomicAdd(&stats[128 + t], s2);
  }
}

// inline BN-prep (redundant per block, 128 rsqrt) + normalize + ReLU
__global__ __launch_bounds__(256) void k_bnapply(float* __restrict__ out,
                                                 const float* __restrict__ stats,
                                                 const float* __restrict__ gamma,
                                                 const float* __restrict__ beta,
                                                 float inv_m, int total4) {
  __shared__ float sc[128], sh[128];
  int t = threadIdx.x;
  if (t < 128) {
    float mu = stats[t] * inv_m;
    float var = stats[128 + t] * inv_m - mu * mu;
    var = fmaxf(var, 0.f);
    float s = gamma[t] * rsqrtf(var + 1e-5f);
    sc[t] = s;
    sh[t] = beta[t] - mu * s;
  }
  __syncthreads();
  const float4* sc4 = (const float4*)sc;
  const float4* sh4 = (const float4*)sh;
  float4* o4 = (float4*)out;
  for (int i = blockIdx.x * blockDim.x + t; i < total4;
       i += gridDim.x * blockDim.x) {
    float4 v = o4[i];
    float4 s = sc4[i & 31];
    float4 h = sh4[i & 31];
    v.x = fmaxf(fmaf(v.x, s.x, h.x), 0.f);
    v.y = fmaxf(fmaf(v.y, s.y, h.y), 0.f);
    v.z = fmaxf(fmaf(v.z, s.z, h.z), 0.f);
    v.w = fmaxf(fmaf(v.w, s.w, h.w), 0.f);
    o4[i] = v;
  }
}

static inline size_t align256(size_t x) { return (x + 255) & ~(size_t)255; }

extern "C" void kernel_launch(void* const* d_in, const int* in_sizes, int n_in,
                              void* d_out, int out_size, void* d_ws, size_t ws_size,
                              hipStream_t stream) {
  const float* ref_bxyz   = (const float*)d_in[0];
  const float* ref_feat   = (const float*)d_in[1];
  const float* query_bxyz = (const float*)d_in[2];
  const int*   e_ref      = (const int*)d_in[3];
  const int*   e_query    = (const int*)d_in[4];
  const float* W_pos      = (const float*)d_in[5];
  const float* b_pos      = (const float*)d_in[6];
  const float* W_mlp      = (const float*)d_in[7];
  const float* b_mlp      = (const float*)d_in[8];
  const float* gamma      = (const float*)d_in[9];
  const float* beta       = (const float*)d_in[10];

  int N_ = in_sizes[0] / 4;
  int M_ = in_sizes[2] / 4;
  int E_ = in_sizes[3];

  char* ws = (char*)d_ws;
  size_t off = 0;
  int*   head   = (int*)(ws + off);   off += align256((size_t)M_ * 4);
  int2*  node   = (int2*)(ws + off);  off += align256((size_t)E_ * 8);
  float* stats  = (float*)(ws + off); off += align256(2 * 128 * 4);
  uint4* featb  = (uint4*)(ws + off);

  hipMemsetAsync(head, 0xFF, (size_t)M_ * 4, stream);     // head[q] = -1

  float* out = (float*)d_out;
  int n8 = N_ * 16;                 // uint4 groups (8 floats each)
  int nwork = (E_ > n8) ? E_ : n8;

  k_build_cvt<<<(nwork + 255) / 256, 256, 0, stream>>>(
      e_query, e_ref, head, node, (const float4*)ref_feat, featb, stats, E_, n8);
  k_fused<<<(M_ + 31) / 32, 256, 0, stream>>>(head, node, featb, ref_bxyz,
                                              query_bxyz, W_mlp, W_pos, b_mlp,
                                              b_pos, out, stats, M_);
  k_bnapply<<<1024, 256, 0, stream>>>(out, stats, gamma, beta, 1.f / (float)M_,
                                      M_ * 32);
}